// Round 7
// baseline (103.175 us; speedup 1.0000x reference)
//
#include <hip/hip_runtime.h>

#define VDIM   32
#define NPAIR  496              // 32*31/2
#define NBASIS 14               // DEG + ORDER - 1
#define NPARAM (NBASIS * NPAIR) // 6944
#define LROW   544              // padded lam row: seg(31)+31 = 543

typedef float f32x4 __attribute__((ext_vector_type(4)));

// Start of row v's segment in the quad-aligned lam layout (multiple of 4):
__device__ __forceinline__ int seg_of(int v) {
    int m = v - 1;
    if (m <= 0) return 0;
    int q = m >> 2, r = m & 3;
    return 4 * (2 * q * (q + 1) + r * (q + 1));
}

// Single kernel. One lm-row per WAVE (4 rows / 256-thr block), rolled loops,
// no __syncthreads, params gathered directly (28 KB -> L1-resident).
// Block 0 additionally computes the three penalty scalars.
__global__ __launch_bounds__(256, 8) void Decorrelation_35270271435435_kernel(
    const float* __restrict__ input,    // [N,32]
    const float* __restrict__ params,   // [14,496] k-major
    float* __restrict__ out,            // [N,32]
    float* __restrict__ lm,             // [N,32,32]
    float* __restrict__ pens,           // [3]
    int N)
{
    __shared__ float lam[4][LROW];      // 8.7 KB; strip per wave

    const int tid  = threadIdx.x;
    const int wave = tid >> 6;
    const int lane = tid & 63;
    const int n    = blockIdx.x * 4 + wave;

    const float invd  = 11.0f / 30.0f;                 // 1/knot-spacing
    const float t0    = -15.0f - 3.0f * (30.0f / 11.0f); // knots[0]
    const float sixth = 1.0f / 6.0f;

    if (n < N) {
        const float* xrow = input + n * VDIM;

        // ---- Phase A: 496 lam values, 8 slots per lane, rolled ----
        for (int k = 0; k < 8; ++k) {
            const int  p  = lane + (k << 6);
            const bool a  = (p < NPAIR);
            const int  pe = a ? p : (NPAIR - 1);
            // pair decode: v = row, c = col of strictly-lower pair pe
            int v = (int)((1.0f + sqrtf(8.0f * (float)pe + 1.0f)) * 0.5f);
            v -= (v * (v - 1) / 2 > pe) ? 1 : 0;
            v += ((v + 1) * v / 2 <= pe) ? 1 : 0;
            const int c = pe - v * (v - 1) / 2;
            const int o = seg_of(v) + c;
            // cubic B-spline weights at x_c (uniform knots)
            const float xi = xrow[c];                  // L1 broadcast (128 B row)
            float x = fminf(fmaxf(xi, -15.0f), 15.0f - 1e-6f);
            float u = (x - t0) * invd;
            int   i = (int)floorf(u);
            i = min(13, max(3, i));
            const float uu  = u - (float)i;
            const float om  = 1.0f - uu;
            const float uu2 = uu * uu, uu3 = uu2 * uu;
            const float w0 = om * om * om * sixth;
            const float w1 = fmaf(3.0f, uu3, fmaf(-6.0f, uu2, 4.0f)) * sixth;
            const float w2 = fmaf(-3.0f, uu3, fmaf(3.0f, uu2, fmaf(3.0f, uu, 1.0f))) * sixth;
            const float w3 = uu3 * sixth;
            // 4 taps straight from params (L1-hot; lanes contiguous in p)
            const int b = (i - 3) * NPAIR + pe;
            const float lv = w0 * params[b]
                           + w1 * params[b + NPAIR]
                           + w2 * params[b + 2 * NPAIR]
                           + w3 * params[b + 3 * NPAIR];
            if (a) lam[wave][o] = lv;
        }

        // ---- Phase B: same wave (waitcnt only, no barrier) — stream the row ----
        float* lmrow = lm + (size_t)n * (VDIM * VDIM);
        for (int j = 0; j < 4; ++j) {
            const int v  = j * 8 + (lane >> 3);
            const int c0 = (lane & 7) << 2;
            const f32x4 lq = *(const f32x4*)&lam[wave][seg_of(v) + c0];
            const f32x4 xq = *(const f32x4*)(xrow + c0);
            float vals[4];
            float partial = 0.0f;
            #pragma unroll
            for (int t = 0; t < 4; ++t) {
                const int c = c0 + t;
                const float lv = (t == 0) ? lq.x : (t == 1) ? lq.y : (t == 2) ? lq.z : lq.w;
                const float xv = (t == 0) ? xq.x : (t == 1) ? xq.y : (t == 2) ? xq.z : xq.w;
                const float val = (c < v) ? lv : ((c == v) ? 1.0f : 0.0f);
                vals[t] = val;
                partial = fmaf(val, xv, partial);
            }
            f32x4 f4 = { vals[0], vals[1], vals[2], vals[3] };
            *(f32x4*)(lmrow + (j << 8) + (lane << 2)) = f4;   // whole 1 KB per instr

            partial += __shfl_down(partial, 4, 8);
            partial += __shfl_down(partial, 2, 8);
            partial += __shfl_down(partial, 1, 8);
            if ((lane & 7) == 0) out[n * VDIM + v] = partial;
        }
    }

    // ---- Penalties: block 0 only (params L1/L2-hot, 6944 floats) ----
    if (blockIdx.x == 0) {
        float s2 = 0.f, s1 = 0.f, sp = 0.f;
        for (int idx = tid; idx < NPARAM; idx += 256) {
            const float a = params[idx];
            sp = fmaf(a, a, sp);
            if (idx < NPARAM - NPAIR) {
                const float b = params[idx + NPAIR];
                const float d1 = b - a;
                s1 = fmaf(d1, d1, s1);
                if (idx < NPARAM - 2 * NPAIR) {
                    const float c = params[idx + 2 * NPAIR];
                    const float d2 = c - 2.f * b + a;
                    s2 = fmaf(d2, d2, s2);
                }
            }
        }
        #pragma unroll
        for (int off = 32; off > 0; off >>= 1) {
            s2 += __shfl_down(s2, off);
            s1 += __shfl_down(s1, off);
            sp += __shfl_down(sp, off);
        }
        __shared__ float ws[3][4];
        if (lane == 0) { ws[0][wave] = s2; ws[1][wave] = s1; ws[2][wave] = sp; }
        __syncthreads();
        if (tid == 0) {
            pens[0] = ws[0][0] + ws[0][1] + ws[0][2] + ws[0][3];
            pens[1] = ws[1][0] + ws[1][1] + ws[1][2] + ws[1][3];
            pens[2] = ws[2][0] + ws[2][1] + ws[2][2] + ws[2][3];
        }
    }
}

extern "C" void kernel_launch(void* const* d_in, const int* in_sizes, int n_in,
                              void* d_out, int out_size, void* d_ws, size_t ws_size,
                              hipStream_t stream) {
    const float* input  = (const float*)d_in[0];   // [N,32]
    // d_in[1] = log_d : unused by the reference
    const float* params = (const float*)d_in[2];   // [14,496]
    const int N = in_sizes[0] / VDIM;              // 16384

    float* out  = (float*)d_out;                   // [N,32]
    float* lm   = out + (size_t)N * VDIM;          // [N,32,32]
    float* pens = lm + (size_t)N * VDIM * VDIM;    // [3]

    const int nb = (N + 3) / 4;                    // 4096 blocks, 1 row/wave
    Decorrelation_35270271435435_kernel<<<nb, 256, 0, stream>>>(
        input, params, out, lm, pens, N);
}